// Round 7
// baseline (297.212 us; speedup 1.0000x reference)
//
#include <hip/hip_runtime.h>
#include <hip/hip_bf16.h>
#include <stdint.h>
#include <math.h>

typedef __attribute__((ext_vector_type(8))) short bf16x8;
typedef __attribute__((ext_vector_type(4))) float f32x4;

#define D_K 256
#define JCHUNK 2048
#define SB 256              // superblock j-width (per wave)
#define NSB (JCHUNK / SB)   // 8
#define NST (SB / 16)       // 16 MFMA subtiles per superblock

__device__ __forceinline__ unsigned short f2bf(float f) {
    unsigned u = __float_as_uint(f);
    u += 0x7fffu + ((u >> 16) & 1u);   // round-to-nearest-even
    return (unsigned short)(u >> 16);
}

// ---------------- Kernel 1: row-normalize z -> bf16; zero partials ----------------
__global__ void normalize_k(const float* __restrict__ z,
                            unsigned short* __restrict__ zn,
                            float* __restrict__ part, int N) {
    int gid  = blockIdx.x * blockDim.x + threadIdx.x;
    if (gid < 5 * N) part[gid] = 0.f;      // stream-ordered before fused_k
    int gw   = gid >> 6;                   // one wave per row
    int lane = threadIdx.x & 63;
    if (gw >= N) return;
    float4 v = reinterpret_cast<const float4*>(z + (size_t)gw * D_K)[lane];
    float ss = v.x * v.x + v.y * v.y + v.z * v.z + v.w * v.w;
#pragma unroll
    for (int m = 32; m; m >>= 1) ss += __shfl_xor(ss, m);
    float sc = 1.0f / fmaxf(sqrtf(ss), 1e-8f);
    ushort4 o;
    o.x = f2bf(v.x * sc); o.y = f2bf(v.y * sc);
    o.z = f2bf(v.z * sc); o.w = f2bf(v.w * sc);
    reinterpret_cast<ushort4*>(zn + (size_t)gw * D_K)[lane] = o;
}

// ---------------- Kernel 2: two-phase fused kernel, zero barriers ----------------
// Each WAVE independently owns 16 i-rows x JCHUNK j. Per 256-j superblock:
//   phase 1: MFMA sim (A = persistent i-frags regs; B = j-frags direct from
//            L2-resident zn), exp->accden, sim (f32) -> wave-private LDS slice.
//   phase 2: stream adj/tsim with 1KB-contiguous per-row runs (16-lane group
//            per row, 4x f32x4), dot vs LDS sim, accumulate row partials.
// No __syncthreads anywhere: LDS slices are wave-private, DS pipe is in-order
// per wave. part: [0,N) den | [N,2N) S1 | [2N,3N) A | [3N,4N) T1 | [4N,5N) T
__global__ __launch_bounds__(256, 2) void fused_k(
    const unsigned short* __restrict__ zn,
    const float* __restrict__ adj,
    const float* __restrict__ tsim,
    float* __restrict__ part, int N) {
    __shared__ float simL[4][16][256];     // 64 KB: per-wave 16x256 f32 sim slice

    const float INV_T = 1.0f / 0.07f;
    const int NIB = N >> 6;                // 128 i-blocks of 64
    int bid = blockIdx.x;
    int ib  = bid & (NIB - 1);
    int jc  = bid / NIB;                   // 0..3
    int tid = threadIdx.x;
    int wid = tid >> 6, lane = tid & 63;
    int l15 = lane & 15, lhi = lane >> 4;
    int i0w = ib * 64 + wid * 16;          // this wave's 16 i-rows
    int jb  = jc * JCHUNK;

    // persistent A-frags: zn rows i0w..i0w+15 (32 VGPRs, loaded once)
    bf16x8 afr[8];
    {
        const bf16x8* ap_ =
            reinterpret_cast<const bf16x8*>(zn + (size_t)(i0w + l15) * D_K) + lhi;
#pragma unroll
        for (int ks = 0; ks < 8; ++ks) afr[ks] = ap_[ks * 4];
    }

    // per-lane partials for rows i0w + lhi*4 + r (r=0..3); reduced across l15 at end
    float accden[4] = {0.f, 0.f, 0.f, 0.f};
    float s1p[4]    = {0.f, 0.f, 0.f, 0.f};
    float app[4]    = {0.f, 0.f, 0.f, 0.f};
    float t1p[4]    = {0.f, 0.f, 0.f, 0.f};
    float ttp[4]    = {0.f, 0.f, 0.f, 0.f};

    float (*sim)[256] = simL[wid];

    for (int sb = 0; sb < NSB; ++sb) {
        int jsb = jb + sb * SB;

        // ---------- phase 1: sim for 16 i x 256 j ----------
#pragma unroll 2
        for (int st = 0; st < NST; ++st) {
            int j0 = jsb + st * 16;
            const bf16x8* bp_ =
                reinterpret_cast<const bf16x8*>(zn + (size_t)(j0 + l15) * D_K) + lhi;
            bf16x8 bfr[8];
#pragma unroll
            for (int ks = 0; ks < 8; ++ks) bfr[ks] = bp_[ks * 4];
            f32x4 acc = (f32x4){0.f, 0.f, 0.f, 0.f};
#pragma unroll
            for (int ks = 0; ks < 8; ++ks)
                acc = __builtin_amdgcn_mfma_f32_16x16x32_bf16(afr[ks], bfr[ks], acc, 0, 0, 0);
            // C/D: col j = j0 + l15, row i = i0w + lhi*4 + r
#pragma unroll
            for (int r = 0; r < 4; ++r) {
                float sv = acc[r] * INV_T;
                int gi = i0w + lhi * 4 + r;
                accden[r] += (gi == j0 + l15) ? 0.f : __expf(sv);
                sim[lhi * 4 + r][st * 16 + l15] = sv;
            }
        }

        // ---------- phase 2: stream adj/tsim, 1KB-contiguous per row-visit ----------
        // 16-lane group lhi handles rows rl = lhi*4 + rg; lane covers 16B + q*256B
#pragma unroll
        for (int rg = 0; rg < 4; ++rg) {
            int rl = lhi * 4 + rg;
            const float* ar = adj  + (size_t)(i0w + rl) * N + jsb + l15 * 4;
            const float* tr = tsim + (size_t)(i0w + rl) * N + jsb + l15 * 4;
            const float* sr = &sim[rl][l15 * 4];
#pragma unroll
            for (int q = 0; q < 4; ++q) {
                f32x4 a = __builtin_nontemporal_load(
                    reinterpret_cast<const f32x4*>(ar + q * 64));
                f32x4 t = __builtin_nontemporal_load(
                    reinterpret_cast<const f32x4*>(tr + q * 64));
                f32x4 s = *reinterpret_cast<const f32x4*>(sr + q * 64);
                s1p[rg] = fmaf(a[0], s[0], fmaf(a[1], s[1],
                          fmaf(a[2], s[2], fmaf(a[3], s[3], s1p[rg]))));
                t1p[rg] = fmaf(t[0], s[0], fmaf(t[1], s[1],
                          fmaf(t[2], s[2], fmaf(t[3], s[3], t1p[rg]))));
                app[rg] += (a[0] + a[1]) + (a[2] + a[3]);
                ttp[rg] += (t[0] + t[1]) + (t[2] + t[3]);
            }
        }
    }

    // ---------- final: reduce across 16 lanes per lhi-group, atomics ----------
#pragma unroll
    for (int r = 0; r < 4; ++r) {
        float d = accden[r], s = s1p[r], a = app[r], u = t1p[r], w = ttp[r];
#pragma unroll
        for (int m = 1; m < 16; m <<= 1) {
            d += __shfl_xor(d, m); s += __shfl_xor(s, m); a += __shfl_xor(a, m);
            u += __shfl_xor(u, m); w += __shfl_xor(w, m);
        }
        if (l15 == 0) {
            int gi = i0w + lhi * 4 + r;
            atomicAdd(part + gi, d);
            atomicAdd(part + (size_t)N + gi, s);
            atomicAdd(part + (size_t)2 * N + gi, a);
            atomicAdd(part + (size_t)3 * N + gi, u);
            atomicAdd(part + (size_t)4 * N + gi, w);
        }
    }
}

// ---------------- Kernel 3: finalize scalar ----------------
__global__ void finalize_k(const float* __restrict__ part, float* __restrict__ out, int N) {
    const float* den = part;
    const float* s1  = part + (size_t)N;
    const float* aa  = part + (size_t)2 * N;
    const float* t1  = part + (size_t)3 * N;
    const float* tt  = part + (size_t)4 * N;
    float acc = 0.f;
    for (int i = threadIdx.x; i < N; i += blockDim.x) {
        float ld = logf(den[i] + 1e-8f);
        acc += -(s1[i] - ld * aa[i]) / (aa[i] + 1e-8f)
               - (t1[i] - ld * tt[i]) / (tt[i] + 1e-8f);
    }
#pragma unroll
    for (int m = 32; m; m >>= 1) acc += __shfl_xor(acc, m);
    __shared__ float red[16];
    if ((threadIdx.x & 63) == 0) red[threadIdx.x >> 6] = acc;
    __syncthreads();
    if (threadIdx.x == 0) {
        float tot = 0.f;
        int nw = blockDim.x >> 6;
        for (int w = 0; w < nw; ++w) tot += red[w];
        out[0] = tot / (float)N;
    }
}

extern "C" void kernel_launch(void* const* d_in, const int* in_sizes, int n_in,
                              void* d_out, int out_size, void* d_ws, size_t ws_size,
                              hipStream_t stream) {
    const float* z    = (const float*)d_in[0];
    const float* adj  = (const float*)d_in[1];
    const float* tsim = (const float*)d_in[2];

    int N = (int)(sqrt((double)in_sizes[1]) + 0.5);  // 8192

    unsigned short* zn = (unsigned short*)d_ws;                   // 4 MB
    float* part = (float*)((char*)d_ws + (size_t)N * D_K * 2);    // 5*N f32

    normalize_k<<<N / 4, 256, 0, stream>>>(z, zn, part, N);

    int nblocks = (N >> 6) * (N / JCHUNK);  // 128 * 4 = 512
    fused_k<<<nblocks, 256, 0, stream>>>(zn, adj, tsim, part, N);

    finalize_k<<<1, 1024, 0, stream>>>(part, (float*)d_out, N);
}

// Round 8
// 172.478 us; speedup vs baseline: 1.7232x; 1.7232x over previous
//
#include <hip/hip_runtime.h>
#include <hip/hip_bf16.h>
#include <stdint.h>
#include <math.h>

typedef __attribute__((ext_vector_type(8))) short bf16x8;
typedef __attribute__((ext_vector_type(4))) float f32x4;

#define D_K 256
#define JCHUNK 2048
#define SB 256              // superblock j-width (phase alternation unit)
#define NSB (JCHUNK / SB)   // 8
#define BT 32               // MFMA subtile j-width (staged tile rows)
#define NST (SB / BT)       // 8 subtiles per superblock

__device__ __forceinline__ unsigned short f2bf(float f) {
    unsigned u = __float_as_uint(f);
    u += 0x7fffu + ((u >> 16) & 1u);   // round-to-nearest-even
    return (unsigned short)(u >> 16);
}
__device__ __forceinline__ float bf2f(unsigned short u) {
    return __uint_as_float(((unsigned)u) << 16);
}
__device__ __forceinline__ void gload_lds16(const void* g, void* l) {
    __builtin_amdgcn_global_load_lds(
        (const __attribute__((address_space(1))) void*)g,
        (__attribute__((address_space(3))) void*)l,
        16, 0, 0);
}

// ---------------- Kernel 1: row-normalize z -> bf16; zero partials ----------------
__global__ void normalize_k(const float* __restrict__ z,
                            unsigned short* __restrict__ zn,
                            float* __restrict__ part, int N) {
    int gid  = blockIdx.x * blockDim.x + threadIdx.x;
    if (gid < 5 * N) part[gid] = 0.f;      // stream-ordered before fused_k
    int gw   = gid >> 6;                   // one wave per row
    int lane = threadIdx.x & 63;
    if (gw >= N) return;
    float4 v = reinterpret_cast<const float4*>(z + (size_t)gw * D_K)[lane];
    float ss = v.x * v.x + v.y * v.y + v.z * v.z + v.w * v.w;
#pragma unroll
    for (int m = 32; m; m >>= 1) ss += __shfl_xor(ss, m);
    float sc = 1.0f / fmaxf(sqrtf(ss), 1e-8f);
    ushort4 o;
    o.x = f2bf(v.x * sc); o.y = f2bf(v.y * sc);
    o.z = f2bf(v.z * sc); o.w = f2bf(v.w * sc);
    reinterpret_cast<ushort4*>(zn + (size_t)gw * D_K)[lane] = o;
}

// Stage one 32-row x 256-d bf16 zn tile (16 KB) into LDS in [kslot][row][16B]
// layout (R6-proven: 0 bank conflicts). gload_lds dest linear; remap on source.
__device__ __forceinline__ void stage_zn(char* dst, const unsigned short* zn,
                                         int j0, int tid, int wid) {
#pragma unroll
    for (int it = 0; it < 4; ++it) {
        int li    = it * 4096 + tid * 16;
        int kslot = li >> 9;          // 0..31
        int row   = (li >> 4) & 31;   // 0..31
        const char* src = reinterpret_cast<const char*>(zn) +
                          ((size_t)(j0 + row) << 9) + (size_t)kslot * 16;
        gload_lds16(src, dst + it * 4096 + wid * 1024);
    }
}

// ---------------- Kernel 2: two-phase fused kernel ----------------
// Per block (4 waves, 64 i-rows, JCHUNK=2048 j): for each 256-j superblock:
//  phase 1 (8 staged subtiles, R6 structure): MFMA sim, exp->accden, park sim
//          as bf16 in wave-private LDS slice (16 i x 256 j, XOR-swizzled).
//  phase 2 (barrier-free): stream adj/tsim with 1KB-contiguous per-row runs
//          (16-lane group per row, 2x 512B group-reads), dot vs parked sim.
// part: [0,N) den | [N,2N) S1 | [2N,3N) A | [3N,4N) T1 | [4N,5N) T
__global__ __launch_bounds__(256, 2) void fused_k(
    const unsigned short* __restrict__ zn,
    const float* __restrict__ adj,
    const float* __restrict__ tsim,
    float* __restrict__ part, int N) {
    __shared__ alignas(128) char stageL[2][BT * 512];   // 2 x 16 KB
    __shared__ alignas(128) char parkL[4][16 * 512];    // 4 waves x 8 KB bf16 park

    const float INV_T = 1.0f / 0.07f;
    const int NIB = N >> 6;
    int ib  = blockIdx.x & (NIB - 1);
    int jc  = blockIdx.x / NIB;            // 0..3
    int tid = threadIdx.x;
    int wid = tid >> 6, lane = tid & 63;
    int l15 = lane & 15, lhi = lane >> 4;
    int i0w = ib * 64 + wid * 16;          // this wave's 16 i-rows
    int gi  = i0w + l15;                   // phase-1 output col = i-row
    int jb  = jc * JCHUNK;
    char* parkW = parkL[wid];

    // B-operand fragments: zn row gi in registers for whole kernel (32 VGPRs)
    bf16x8 bfr[8];
    {
        const bf16x8* bp = reinterpret_cast<const bf16x8*>(zn + (size_t)gi * D_K) + lhi;
#pragma unroll
        for (int ks = 0; ks < 8; ++ks) bfr[ks] = bp[ks * 4];
    }

    float accden = 0.f;                       // den partial for i-row gi
    float s1p[4] = {0.f, 0.f, 0.f, 0.f};      // phase-2 partials, row rg*4+lhi
    float app[4] = {0.f, 0.f, 0.f, 0.f};
    float t1p[4] = {0.f, 0.f, 0.f, 0.f};
    float ttp[4] = {0.f, 0.f, 0.f, 0.f};

    // prologue: stage first subtile
    stage_zn(stageL[0], zn, jb, tid, wid);
    asm volatile("s_waitcnt vmcnt(0)" ::: "memory");
    __syncthreads();
    int cur = 0;

    for (int sb = 0; sb < NSB; ++sb) {
        int jsb = jb + sb * SB;

        // ---------- phase 1: sim for 64 i x 256 j (this wave: 16 i) ----------
        for (int st = 0; st < NST; ++st) {
            // stage next subtile (or first subtile of next superblock)
            int nj = jsb + (st + 1) * BT;          // next within sb, or == next sb start
            if (sb + 1 < NSB || st + 1 < NST)
                stage_zn(stageL[cur ^ 1], zn, nj, tid, wid);

            const char* buf = stageL[cur];
            f32x4 acc[2] = {(f32x4){0.f,0.f,0.f,0.f}, (f32x4){0.f,0.f,0.f,0.f}};
#pragma unroll
            for (int ks = 0; ks < 8; ++ks) {
#pragma unroll
                for (int t = 0; t < 2; ++t) {
                    int boff = (ks << 11) + (lhi << 9) + (t << 8) + (l15 << 4);
                    bf16x8 aj = *reinterpret_cast<const bf16x8*>(buf + boff);
                    acc[t] = __builtin_amdgcn_mfma_f32_16x16x32_bf16(aj, bfr[ks], acc[t], 0, 0, 0);
                }
            }
            // exp->den, park sim as bf16 (8B packed write, XOR-swizzled by i-row)
#pragma unroll
            for (int t = 0; t < 2; ++t) {
                int jcol = st * BT + t * 16 + lhi * 4;   // j within superblock
                float sv[4];
#pragma unroll
                for (int r = 0; r < 4; ++r) {
                    sv[r] = acc[t][r] * INV_T;
                    int gj = jsb + jcol + r;
                    accden += (gi == gj) ? 0.f : __expf(sv[r]);
                }
                ushort4 pk;
                pk.x = f2bf(sv[0]); pk.y = f2bf(sv[1]);
                pk.z = f2bf(sv[2]); pk.w = f2bf(sv[3]);
                *reinterpret_cast<ushort4*>(
                    parkW + l15 * 512 + ((jcol * 2) ^ ((l15 & 7) << 4))) = pk;
            }
            asm volatile("s_waitcnt vmcnt(0)" ::: "memory");
            __syncthreads();
            cur ^= 1;
        }

        // ---------- phase 2: stream adj/tsim, 1KB-contiguous per row ----------
        // group lhi handles i-rows rg*4+lhi; lane reads 32B per row per q.
#pragma unroll
        for (int rg = 0; rg < 4; ++rg) {
            int irow = rg * 4 + lhi;
            const float* ar = adj  + (size_t)(i0w + irow) * N + jsb + l15 * 8;
            const float* tr = tsim + (size_t)(i0w + irow) * N + jsb + l15 * 8;
            const char*  pr = parkW + irow * 512;
            int sx = (irow & 7) << 4;
#pragma unroll
            for (int q = 0; q < 2; ++q) {
                f32x4 a0 = __builtin_nontemporal_load(
                    reinterpret_cast<const f32x4*>(ar + q * 128));
                f32x4 a1 = __builtin_nontemporal_load(
                    reinterpret_cast<const f32x4*>(ar + q * 128 + 4));
                f32x4 t0 = __builtin_nontemporal_load(
                    reinterpret_cast<const f32x4*>(tr + q * 128));
                f32x4 t1 = __builtin_nontemporal_load(
                    reinterpret_cast<const f32x4*>(tr + q * 128 + 4));
                bf16x8 s8 = *reinterpret_cast<const bf16x8*>(
                    pr + ((l15 * 16 + q * 256) ^ sx));
                float s[8];
#pragma unroll
                for (int e = 0; e < 8; ++e) s[e] = bf2f((unsigned short)s8[e]);
                float s1 = s1p[rg], t1v = t1p[rg];
#pragma unroll
                for (int e = 0; e < 4; ++e) {
                    s1  = fmaf(a0[e], s[e], s1);
                    s1  = fmaf(a1[e], s[4 + e], s1);
                    t1v = fmaf(t0[e], s[e], t1v);
                    t1v = fmaf(t1[e], s[4 + e], t1v);
                }
                s1p[rg] = s1; t1p[rg] = t1v;
                app[rg] += (a0[0] + a0[1] + a0[2] + a0[3]) +
                           (a1[0] + a1[1] + a1[2] + a1[3]);
                ttp[rg] += (t0[0] + t0[1] + t0[2] + t0[3]) +
                           (t1[0] + t1[1] + t1[2] + t1[3]);
            }
        }
    }

    // ---------- final reductions + atomics ----------
    // den: lanes lhi=0..3 share i-row gi
    accden += __shfl_xor(accden, 16); accden += __shfl_xor(accden, 32);
    if (lhi == 0) atomicAdd(part + gi, accden);
    // phase-2 partials: 16 lanes (l15) share row rg*4+lhi
#pragma unroll
    for (int rg = 0; rg < 4; ++rg) {
        float s = s1p[rg], a = app[rg], u = t1p[rg], w = ttp[rg];
#pragma unroll
        for (int m = 1; m < 16; m <<= 1) {
            s += __shfl_xor(s, m); a += __shfl_xor(a, m);
            u += __shfl_xor(u, m); w += __shfl_xor(w, m);
        }
        if (l15 == 0) {
            int gr = i0w + rg * 4 + lhi;
            atomicAdd(part + (size_t)N + gr, s);
            atomicAdd(part + (size_t)2 * N + gr, a);
            atomicAdd(part + (size_t)3 * N + gr, u);
            atomicAdd(part + (size_t)4 * N + gr, w);
        }
    }
}

// ---------------- Kernel 3: finalize scalar ----------------
__global__ void finalize_k(const float* __restrict__ part, float* __restrict__ out, int N) {
    const float* den = part;
    const float* s1  = part + (size_t)N;
    const float* aa  = part + (size_t)2 * N;
    const float* t1  = part + (size_t)3 * N;
    const float* tt  = part + (size_t)4 * N;
    float acc = 0.f;
    for (int i = threadIdx.x; i < N; i += blockDim.x) {
        float ld = logf(den[i] + 1e-8f);
        acc += -(s1[i] - ld * aa[i]) / (aa[i] + 1e-8f)
               - (t1[i] - ld * tt[i]) / (tt[i] + 1e-8f);
    }
#pragma unroll
    for (int m = 32; m; m >>= 1) acc += __shfl_xor(acc, m);
    __shared__ float red[16];
    if ((threadIdx.x & 63) == 0) red[threadIdx.x >> 6] = acc;
    __syncthreads();
    if (threadIdx.x == 0) {
        float tot = 0.f;
        int nw = blockDim.x >> 6;
        for (int w = 0; w < nw; ++w) tot += red[w];
        out[0] = tot / (float)N;
    }
}

extern "C" void kernel_launch(void* const* d_in, const int* in_sizes, int n_in,
                              void* d_out, int out_size, void* d_ws, size_t ws_size,
                              hipStream_t stream) {
    const float* z    = (const float*)d_in[0];
    const float* adj  = (const float*)d_in[1];
    const float* tsim = (const float*)d_in[2];

    int N = (int)(sqrt((double)in_sizes[1]) + 0.5);  // 8192

    unsigned short* zn = (unsigned short*)d_ws;                   // 4 MB
    float* part = (float*)((char*)d_ws + (size_t)N * D_K * 2);    // 5*N f32

    normalize_k<<<N / 4, 256, 0, stream>>>(z, zn, part, N);

    int nblocks = (N >> 6) * (N / JCHUNK);  // 128 * 4 = 512
    fused_k<<<nblocks, 256, 0, stream>>>(zn, adj, tsim, part, N);

    finalize_k<<<1, 1024, 0, stream>>>(part, (float*)d_out, N);
}